// Round 10
// baseline (399.772 us; speedup 1.0000x reference)
//
#include <hip/hip_runtime.h>
#include <cstddef>

// ---------------------------------------------------------------------------
// Fused transformer block (B=4, N=2048, C=768, H=12, D=64, HIDDEN=3072)
// R10: attention re-tiled for LDS bandwidth (the R9 post-mortem bound):
//      128-thread blocks, 2 waves x 64 queries (qc=4) — halves per-CU LDS
//      read traffic per query (every wave must read the whole K/V tile, so
//      fewer+fatter waves win). exp->PV interleaved per kc to cap registers.
//      GEMMs unchanged (R6 2-barrier TM=128/64 mix). P stays in registers
//      (16x16x16 PV). dbuf K/V + bh-major grid.
// ---------------------------------------------------------------------------

typedef _Float16 h8 __attribute__((ext_vector_type(8)));
typedef _Float16 h4 __attribute__((ext_vector_type(4)));
typedef _Float16 h2 __attribute__((ext_vector_type(2)));
typedef float f4 __attribute__((ext_vector_type(4)));

#define MFMA16(a, b, c) __builtin_amdgcn_mfma_f32_16x16x32_f16((a), (b), (c), 0, 0, 0)
#define MFMAK16(a, b, c) __builtin_amdgcn_mfma_f32_16x16x16f16((a), (b), (c), 0, 0, 0)

__device__ __forceinline__ _Float16 f2h(float x) { return (_Float16)x; }
__device__ __forceinline__ h2 pk2(float a, float b) {
    return __builtin_bit_cast(h2, __builtin_amdgcn_cvt_pkrtz(a, b));
}
__device__ __forceinline__ h4 pk4(float a, float b, float c, float d) {
    h2 p0 = pk2(a, b);
    h2 p1 = pk2(c, d);
    h4 r; r[0] = p0[0]; r[1] = p0[1]; r[2] = p1[0]; r[3] = p1[1];
    return r;
}

// async global->LDS, 16B per lane; LDS dst is wave-uniform base + lane*16
__device__ __forceinline__ void gl_lds16(const _Float16* g, _Float16* l) {
    __builtin_amdgcn_global_load_lds(
        (const __attribute__((address_space(1))) void*)g,
        (__attribute__((address_space(3))) void*)l, 16, 0, 0);
}

// ---------------- weight cast fp32 -> f16 (all four weights, one launch) ----------------
__global__ void cvt_all(const float* __restrict__ s0, _Float16* __restrict__ d0, int n0,
                        const float* __restrict__ s1, _Float16* __restrict__ d1, int n1,
                        const float* __restrict__ s2, _Float16* __restrict__ d2, int n2,
                        const float* __restrict__ s3, _Float16* __restrict__ d3) {
    int i = (blockIdx.x * 256 + threadIdx.x) * 4;
    const float* s; _Float16* d; int base;
    if (i < n0) { s = s0; d = d0; base = 0; }
    else if (i < n0 + n1) { s = s1; d = d1; base = n0; }
    else if (i < n0 + n1 + n2) { s = s2; d = d2; base = n0 + n1; }
    else { s = s3; d = d3; base = n0 + n1 + n2; }
    int j = i - base;
    float4 v = *(const float4*)(s + j);
    *(h4*)(d + j) = pk4(v.x, v.y, v.z, v.w);
}

// ---------------- LayerNorm: fp32 in -> f16 out, one block (192 thr) per row ----------------
__global__ void ln_f16(const float* __restrict__ x, const float* __restrict__ w,
                       const float* __restrict__ b, _Float16* __restrict__ out) {
    int row = blockIdx.x;
    int tid = threadIdx.x;  // 192 threads, 3 waves, 4 floats each = 768
    float4 v = ((const float4*)(x + (size_t)row * 768))[tid];
    float s = v.x + v.y + v.z + v.w;
    float s2 = v.x * v.x + v.y * v.y + v.z * v.z + v.w * v.w;
#pragma unroll
    for (int off = 32; off > 0; off >>= 1) {
        s += __shfl_down(s, off, 64);
        s2 += __shfl_down(s2, off, 64);
    }
    __shared__ float red[6];
    if ((tid & 63) == 0) { red[tid >> 6] = s; red[3 + (tid >> 6)] = s2; }
    __syncthreads();
    s = red[0] + red[1] + red[2];
    s2 = red[3] + red[4] + red[5];
    float mean = s * (1.0f / 768.0f);
    float rstd = rsqrtf(s2 * (1.0f / 768.0f) - mean * mean + 1e-5f);
    float4 wv = ((const float4*)w)[tid];
    float4 bv = ((const float4*)b)[tid];
    *(h4*)(out + (size_t)row * 768 + tid * 4) =
        pk4((v.x - mean) * rstd * wv.x + bv.x, (v.y - mean) * rstd * wv.y + bv.y,
            (v.z - mean) * rstd * wv.z + bv.z, (v.w - mean) * rstd * wv.w + bv.w);
}

// ---------------- MFMA GEMM: C = A @ W^T (+ mode-specific epilogue) ----------------
// A [M,K] f16 row-major; W [Nout,K] f16 row-major. Tile TM x 128, 4 waves, BK=64.
enum { MODE_QKV = 0, MODE_PROJ = 1, MODE_FC1 = 2, MODE_FC2 = 3 };

template <int MODE, int TM>
__global__ __launch_bounds__(256, TM == 64 ? 4 : 3) void gemm_bt(
    const _Float16* __restrict__ A, const _Float16* __restrict__ W,
    const float* __restrict__ bias, const float* __restrict__ resid,
    float* __restrict__ outF, _Float16* __restrict__ oq,
    _Float16* __restrict__ okk, _Float16* __restrict__ ov, int K) {
    constexpr int MI = TM / 32;  // 4 or 2 row-frags per wave
    constexpr int AI = TM / 32;  // staging instrs per wave for A
    __shared__ _Float16 As[TM * 64];
    __shared__ _Float16 Bs[128 * 64];
    int bm = blockIdx.x * TM, bn = blockIdx.y * 128;
    int tid = threadIdx.x;
    int wave = tid >> 6, lane = tid & 63, quad = lane >> 4, l15 = lane & 15;
    int wrow = (wave >> 1) * (TM / 2), wcol = (wave & 1) * 64;
    int lr = lane >> 3;                 // row-within-8 for staging
    int sw = ((lane & 7) ^ lr) * 8;     // swizzled source col (halves)
    int rsw = (l15 & 7) * 8;            // read-side swizzle XOR operand (halves)
    f4 acc[MI][4];
#pragma unroll
    for (int mi = 0; mi < MI; mi++)
#pragma unroll
        for (int ni = 0; ni < 4; ni++) acc[mi][ni] = (f4){0.f, 0.f, 0.f, 0.f};

    const _Float16* ApG[AI];
    _Float16* AsL[AI];
#pragma unroll
    for (int i = 0; i < AI; i++) {
        int r = wave * (TM / 4) + i * 8;
        ApG[i] = A + (size_t)(bm + r + lr) * K + sw;
        AsL[i] = As + r * 64;
    }
    const _Float16* WpG[4];
    _Float16* BsL[4];
#pragma unroll
    for (int i = 0; i < 4; i++) {
        int r = wave * 32 + i * 8;
        WpG[i] = W + (size_t)(bn + r + lr) * K + sw;
        BsL[i] = Bs + r * 64;
    }

    for (int k0 = 0; k0 < K; k0 += 64) {
        __syncthreads();  // previous iter's LDS reads done
#pragma unroll
        for (int i = 0; i < AI; i++) { gl_lds16(ApG[i], AsL[i]); ApG[i] += 64; }
#pragma unroll
        for (int i = 0; i < 4; i++) { gl_lds16(WpG[i], BsL[i]); WpG[i] += 64; }
        __syncthreads();  // vmcnt(0) drain before reads
#pragma unroll
        for (int ks = 0; ks < 2; ks++) {
            h8 af[MI], bfr[4];
#pragma unroll
            for (int mi = 0; mi < MI; mi++)
                af[mi] = *(const h8*)&As[(wrow + 16 * mi + l15) * 64 +
                                         (((4 * ks + quad) * 8) ^ rsw)];
#pragma unroll
            for (int ni = 0; ni < 4; ni++)
                bfr[ni] = *(const h8*)&Bs[(wcol + 16 * ni + l15) * 64 +
                                          (((4 * ks + quad) * 8) ^ rsw)];
#pragma unroll
            for (int mi = 0; mi < MI; mi++)
#pragma unroll
                for (int ni = 0; ni < 4; ni++)
                    acc[mi][ni] = MFMA16(af[mi], bfr[ni], acc[mi][ni]);
        }
    }

    // epilogue: C/D layout col=lane&15, row=quad*4+j
#pragma unroll
    for (int mi = 0; mi < MI; mi++) {
#pragma unroll
        for (int ni = 0; ni < 4; ni++) {
            int col = bn + wcol + 16 * ni + l15;
            float bc = bias[col];
            int m0 = bm + wrow + 16 * mi + quad * 4;
            float v0 = acc[mi][ni][0] + bc, v1 = acc[mi][ni][1] + bc;
            float v2 = acc[mi][ni][2] + bc, v3 = acc[mi][ni][3] + bc;
            if (MODE == MODE_QKV) {
                int sec = col / 768;           // 0=q 1=k 2=v (uniform per block)
                int rem = col - sec * 768;
                int h = rem >> 6, d = rem & 63;
                int b_ = m0 >> 11, ns = m0 & 2047;
                size_t bh = (size_t)(b_ * 12 + h);
                if (sec == 0) {
                    // Q pre-scaled by 1/8 * log2(e) so attention can use exp2
                    size_t base = (bh * 2048 + ns) * 64 + d;
                    oq[base] = f2h(v0 * 0.18033688f);
                    oq[base + 64] = f2h(v1 * 0.18033688f);
                    oq[base + 128] = f2h(v2 * 0.18033688f);
                    oq[base + 192] = f2h(v3 * 0.18033688f);
                } else if (sec == 1) {
                    size_t base = (bh * 2048 + ns) * 64 + d;
                    okk[base] = f2h(v0);
                    okk[base + 64] = f2h(v1);
                    okk[base + 128] = f2h(v2);
                    okk[base + 192] = f2h(v3);
                } else {
                    *(h4*)&ov[(bh * 64 + d) * 2048 + ns] = pk4(v0, v1, v2, v3);  // V^T
                }
            } else if (MODE == MODE_FC1) {
                // tanh-form GELU: x*sigmoid(1.595769x + 0.142954x^3) via exp
                float g0 = __expf(v0 * (1.5957691f + 0.14295405f * v0 * v0));
                float g1 = __expf(v1 * (1.5957691f + 0.14295405f * v1 * v1));
                float g2 = __expf(v2 * (1.5957691f + 0.14295405f * v2 * v2));
                float g3 = __expf(v3 * (1.5957691f + 0.14295405f * v3 * v3));
                size_t base = (size_t)m0 * 3072 + col;
                oq[base] = f2h(v0 * g0 / (1.f + g0));
                oq[base + 3072] = f2h(v1 * g1 / (1.f + g1));
                oq[base + 6144] = f2h(v2 * g2 / (1.f + g2));
                oq[base + 9216] = f2h(v3 * g3 / (1.f + g3));
            } else {  // PROJ / FC2: + residual -> fp32
                size_t idx = (size_t)m0 * 768 + col;
                outF[idx] = v0 + resid[idx];
                outF[idx + 768] = v1 + resid[idx + 768];
                outF[idx + 1536] = v2 + resid[idx + 1536];
                outF[idx + 2304] = v3 + resid[idx + 2304];
            }
        }
    }
}

// ---------------- Flash attention: 2 waves x 64 queries, LDS-BW-tiled ----------------
// Q,K [bh,2048,64] (Q pre-scaled by 0.125*log2e), Vt [bh,64,2048] -> O f16 [B,N,768].
// Block (bh, qt): 128 threads = 2 waves, each wave 64 queries x all 64 keys/tile.
// Every wave must read the whole K/V tile, so queries/wave is the LDS-traffic
// divisor: qc=4 halves per-CU LDS bytes vs R9. exp->PV interleaved per kc.
__global__ __launch_bounds__(128, 2) void attn_kernel(
    const _Float16* __restrict__ Q, const _Float16* __restrict__ Kp,
    const _Float16* __restrict__ Vt, _Float16* __restrict__ O) {
    int bh = blockIdx.x;   // 48
    int qt = blockIdx.y;   // 16 q-tiles of 128
    int tid = threadIdx.x; // 128
    int wv = tid >> 6, lane = tid & 63, quad = lane >> 4, l15 = lane & 15;
    int lr = lane >> 3;
    int sw = ((lane & 7) ^ lr) * 8;  // staging swizzle (halves)
    int rsw = (l15 & 7) * 8;         // read swizzle (halves)

    __shared__ _Float16 Ks[2 * 64 * 64];  // [key][d]  16 KB dbuf, swizzled
    __shared__ _Float16 Vs[2 * 64 * 64];  // [d][key]  16 KB dbuf, swizzled

    // Q fragments: loop-invariant. query = qt*128 + wv*64 + 16*qc + l15
    h8 qf[4][2];
    {
        const _Float16* Qb =
            Q + (((size_t)bh * 2048) + qt * 128 + wv * 64 + l15) * 64 + quad * 8;
#pragma unroll
        for (int qc = 0; qc < 4; qc++)
#pragma unroll
            for (int ks = 0; ks < 2; ks++)
                qf[qc][ks] = *(const h8*)(Qb + qc * 16 * 64 + ks * 32);
    }
    h4 ones4;
#pragma unroll
    for (int j = 0; j < 4; j++) ones4[j] = (_Float16)1.0f;

    f4 Oa[4][4];  // [dc][qc]
    f4 Ls[4];     // ones-MFMA row-sum accumulators
#pragma unroll
    for (int dc = 0; dc < 4; dc++)
#pragma unroll
        for (int qc = 0; qc < 4; qc++) Oa[dc][qc] = (f4){0.f, 0.f, 0.f, 0.f};
#pragma unroll
    for (int qc = 0; qc < 4; qc++) Ls[qc] = (f4){0.f, 0.f, 0.f, 0.f};

    // staging: 2 waves x 4 gl_lds16 cover 64 rows for each of K and V
    const _Float16* Kg = Kp + (size_t)bh * 2048 * 64;
    const _Float16* Vg = Vt + (size_t)bh * 64 * 2048;
    const _Float16* KpG[4];
    const _Float16* VpG[4];
    int rKV[4];
#pragma unroll
    for (int i = 0; i < 4; i++) {
        rKV[i] = wv * 32 + i * 8;
        KpG[i] = Kg + (size_t)(rKV[i] + lr) * 64 + sw;
        VpG[i] = Vg + (size_t)(rKV[i] + lr) * 2048 + sw;
    }

    // prologue: prefetch tile 0 into buffer 0
#pragma unroll
    for (int i = 0; i < 4; i++) {
        gl_lds16(KpG[i], Ks + rKV[i] * 64); KpG[i] += 4096;
        gl_lds16(VpG[i], Vs + rKV[i] * 64); VpG[i] += 64;
    }

    for (int it = 0; it < 32; it++) {
        int bufC = (it & 1) * 4096, bufN = ((it & 1) ^ 1) * 4096;
        __syncthreads();  // this tile's prefetch done; prev-iter reads done
        if (it + 1 < 32) {
#pragma unroll
            for (int i = 0; i < 4; i++) {
                gl_lds16(KpG[i], Ks + bufN + rKV[i] * 64); KpG[i] += 4096;
                gl_lds16(VpG[i], Vs + bufN + rKV[i] * 64); VpG[i] += 64;
            }
        }

        // S^T = K . Q^T  (C-layout: key=quad*4+j within 16-key block kc, query=l15)
        f4 Sa[4][4];  // [kc][qc]
#pragma unroll
        for (int kc = 0; kc < 4; kc++)
#pragma unroll
            for (int qc = 0; qc < 4; qc++) Sa[kc][qc] = (f4){0.f, 0.f, 0.f, 0.f};
#pragma unroll
        for (int ks = 0; ks < 2; ks++) {
            h8 kf[4];
#pragma unroll
            for (int kc = 0; kc < 4; kc++)
                kf[kc] = *(const h8*)&Ks[bufC + (16 * kc + l15) * 64 +
                                         (((4 * ks + quad) * 8) ^ rsw)];
#pragma unroll
            for (int kc = 0; kc < 4; kc++)
#pragma unroll
                for (int qc = 0; qc < 4; qc++)
                    Sa[kc][qc] = MFMA16(kf[kc], qf[qc][ks], Sa[kc][qc]);
        }

        // per kc: exp2 -> p regs (B-operand of 16x16x16) -> PV MFMAs immediately
#pragma unroll
        for (int kc = 0; kc < 4; kc++) {
            h4 p[4];
#pragma unroll
            for (int qc = 0; qc < 4; qc++)
                p[qc] = pk4(exp2f(Sa[kc][qc][0]), exp2f(Sa[kc][qc][1]),
                            exp2f(Sa[kc][qc][2]), exp2f(Sa[kc][qc][3]));
            h4 vf4[4];
#pragma unroll
            for (int dc = 0; dc < 4; dc++)
                vf4[dc] = *(const h4*)&Vs[bufC + (16 * dc + l15) * 64 +
                                          (((2 * kc + (quad >> 1)) * 8) ^ rsw) +
                                          (quad & 1) * 4];
#pragma unroll
            for (int dc = 0; dc < 4; dc++)
#pragma unroll
                for (int qc = 0; qc < 4; qc++)
                    Oa[dc][qc] = MFMAK16(vf4[dc], p[qc], Oa[dc][qc]);
#pragma unroll
            for (int qc = 0; qc < 4; qc++)
                Ls[qc] = MFMAK16(ones4, p[qc], Ls[qc]);
        }
    }

    // epilogue: O[b, n, h*64 + d] f16, d = 16*dc + quad*4 + j
    int b_ = bh / 12, h = bh - b_ * 12;
#pragma unroll
    for (int qc = 0; qc < 4; qc++) {
        float inv = 1.0f / Ls[qc][0];
        int n = qt * 128 + wv * 64 + 16 * qc + l15;
        size_t base = ((size_t)b_ * 2048 + n) * 768 + h * 64;
#pragma unroll
        for (int dc = 0; dc < 4; dc++) {
            f4 o = Oa[dc][qc];
            *(h4*)&O[base + 16 * dc + quad * 4] =
                pk4(o[0] * inv, o[1] * inv, o[2] * inv, o[3] * inv);
        }
    }
}

// ---------------------------------------------------------------------------
extern "C" void kernel_launch(void* const* d_in, const int* in_sizes, int n_in,
                              void* d_out, int out_size, void* d_ws, size_t ws_size,
                              hipStream_t stream) {
    const float* x      = (const float*)d_in[0];
    const float* ln1_w  = (const float*)d_in[1];
    const float* ln1_b  = (const float*)d_in[2];
    const float* qkv_w  = (const float*)d_in[3];
    const float* qkv_b  = (const float*)d_in[4];
    const float* proj_w = (const float*)d_in[5];
    const float* proj_b = (const float*)d_in[6];
    const float* ln2_w  = (const float*)d_in[7];
    const float* ln2_b  = (const float*)d_in[8];
    const float* fc1_w  = (const float*)d_in[9];
    const float* fc1_b  = (const float*)d_in[10];
    const float* fc2_w  = (const float*)d_in[11];
    const float* fc2_b  = (const float*)d_in[12];
    float* out = (float*)d_out;

    // workspace arena (~77 MB)
    char* ws = (char*)d_ws;
    size_t off = 0;
    _Float16* wqkv  = (_Float16*)(ws + off); off += (size_t)2304 * 768 * 2;
    _Float16* wproj = (_Float16*)(ws + off); off += (size_t)768 * 768 * 2;
    _Float16* wfc1  = (_Float16*)(ws + off); off += (size_t)3072 * 768 * 2;
    _Float16* wfc2  = (_Float16*)(ws + off); off += (size_t)768 * 3072 * 2;
    _Float16* actA  = (_Float16*)(ws + off); off += (size_t)8192 * 768 * 2;   // ln1/attn/ln2 out
    _Float16* big   = (_Float16*)(ws + off); off += (size_t)8192 * 3072 * 2;  // q,k,vT | fc1 out
    _Float16* qb = big;
    _Float16* kb = big + (size_t)48 * 2048 * 64;
    _Float16* vb = big + (size_t)2 * 48 * 2048 * 64;
    _Float16* hb = big;  // reused after attention for gelu(fc1) [8192,3072]

    // one launch for all four weight casts
    cvt_all<<<6912, 256, 0, stream>>>(qkv_w, wqkv, 2304 * 768, proj_w, wproj, 768 * 768,
                                      fc1_w, wfc1, 3072 * 768, fc2_w, wfc2);

    ln_f16<<<8192, 192, 0, stream>>>(x, ln1_w, ln1_b, actA);
    gemm_bt<MODE_QKV, 128><<<dim3(64, 18), 256, 0, stream>>>(actA, wqkv, qkv_b, nullptr,
                                                             nullptr, qb, kb, vb, 768);
    attn_kernel<<<dim3(48, 16), 128, 0, stream>>>(qb, kb, vb, actA);
    gemm_bt<MODE_PROJ, 64><<<dim3(128, 6), 256, 0, stream>>>(actA, wproj, proj_b, x, out,
                                                             nullptr, nullptr, nullptr, 768);
    ln_f16<<<8192, 192, 0, stream>>>(out, ln2_w, ln2_b, actA);
    gemm_bt<MODE_FC1, 128><<<dim3(64, 24), 256, 0, stream>>>(actA, wfc1, fc1_b, nullptr,
                                                             nullptr, hb, nullptr, nullptr, 768);
    gemm_bt<MODE_FC2, 64><<<dim3(128, 6), 256, 0, stream>>>(hb, wfc2, fc2_b, out, out,
                                                            nullptr, nullptr, nullptr, 3072);
}

// Round 11
// 356.036 us; speedup vs baseline: 1.1228x; 1.1228x over previous
//
#include <hip/hip_runtime.h>
#include <cstddef>

// ---------------------------------------------------------------------------
// Fused transformer block (B=4, N=2048, C=768, H=12, D=64, HIDDEN=3072)
// R11: attn reverted to R9 (256 thr, 4 waves x 32 queries — R10's fat-wave
//      retile starved the SIMDs at 1.5 waves/SIMD). GEMM now takes TN as a
//      template param; QKV uses 128x192 tiles -> grid 64x12 = 768 blocks
//      (exactly 1 round at 3/CU, vs 1.5 imbalanced rounds before) and +50%
//      MFMA density per wave. fc1/proj/fc2 unchanged (already balanced).
// ---------------------------------------------------------------------------

typedef _Float16 h8 __attribute__((ext_vector_type(8)));
typedef _Float16 h4 __attribute__((ext_vector_type(4)));
typedef _Float16 h2 __attribute__((ext_vector_type(2)));
typedef float f4 __attribute__((ext_vector_type(4)));

#define MFMA16(a, b, c) __builtin_amdgcn_mfma_f32_16x16x32_f16((a), (b), (c), 0, 0, 0)
#define MFMAK16(a, b, c) __builtin_amdgcn_mfma_f32_16x16x16f16((a), (b), (c), 0, 0, 0)

__device__ __forceinline__ _Float16 f2h(float x) { return (_Float16)x; }
__device__ __forceinline__ h2 pk2(float a, float b) {
    return __builtin_bit_cast(h2, __builtin_amdgcn_cvt_pkrtz(a, b));
}
__device__ __forceinline__ h4 pk4(float a, float b, float c, float d) {
    h2 p0 = pk2(a, b);
    h2 p1 = pk2(c, d);
    h4 r; r[0] = p0[0]; r[1] = p0[1]; r[2] = p1[0]; r[3] = p1[1];
    return r;
}

// async global->LDS, 16B per lane; LDS dst is wave-uniform base + lane*16
__device__ __forceinline__ void gl_lds16(const _Float16* g, _Float16* l) {
    __builtin_amdgcn_global_load_lds(
        (const __attribute__((address_space(1))) void*)g,
        (__attribute__((address_space(3))) void*)l, 16, 0, 0);
}

// ---------------- weight cast fp32 -> f16 (all four weights, one launch) ----------------
__global__ void cvt_all(const float* __restrict__ s0, _Float16* __restrict__ d0, int n0,
                        const float* __restrict__ s1, _Float16* __restrict__ d1, int n1,
                        const float* __restrict__ s2, _Float16* __restrict__ d2, int n2,
                        const float* __restrict__ s3, _Float16* __restrict__ d3) {
    int i = (blockIdx.x * 256 + threadIdx.x) * 4;
    const float* s; _Float16* d; int base;
    if (i < n0) { s = s0; d = d0; base = 0; }
    else if (i < n0 + n1) { s = s1; d = d1; base = n0; }
    else if (i < n0 + n1 + n2) { s = s2; d = d2; base = n0 + n1; }
    else { s = s3; d = d3; base = n0 + n1 + n2; }
    int j = i - base;
    float4 v = *(const float4*)(s + j);
    *(h4*)(d + j) = pk4(v.x, v.y, v.z, v.w);
}

// ---------------- LayerNorm: fp32 in -> f16 out, one block (192 thr) per row ----------------
__global__ void ln_f16(const float* __restrict__ x, const float* __restrict__ w,
                       const float* __restrict__ b, _Float16* __restrict__ out) {
    int row = blockIdx.x;
    int tid = threadIdx.x;  // 192 threads, 3 waves, 4 floats each = 768
    float4 v = ((const float4*)(x + (size_t)row * 768))[tid];
    float s = v.x + v.y + v.z + v.w;
    float s2 = v.x * v.x + v.y * v.y + v.z * v.z + v.w * v.w;
#pragma unroll
    for (int off = 32; off > 0; off >>= 1) {
        s += __shfl_down(s, off, 64);
        s2 += __shfl_down(s2, off, 64);
    }
    __shared__ float red[6];
    if ((tid & 63) == 0) { red[tid >> 6] = s; red[3 + (tid >> 6)] = s2; }
    __syncthreads();
    s = red[0] + red[1] + red[2];
    s2 = red[3] + red[4] + red[5];
    float mean = s * (1.0f / 768.0f);
    float rstd = rsqrtf(s2 * (1.0f / 768.0f) - mean * mean + 1e-5f);
    float4 wv = ((const float4*)w)[tid];
    float4 bv = ((const float4*)b)[tid];
    *(h4*)(out + (size_t)row * 768 + tid * 4) =
        pk4((v.x - mean) * rstd * wv.x + bv.x, (v.y - mean) * rstd * wv.y + bv.y,
            (v.z - mean) * rstd * wv.z + bv.z, (v.w - mean) * rstd * wv.w + bv.w);
}

// ---------------- MFMA GEMM: C = A @ W^T (+ mode-specific epilogue) ----------------
// A [M,K] f16 row-major; W [Nout,K] f16 row-major. Tile TM x TN, 4 waves in a
// 2x2 grid (each TM/2 x TN/2), BK=64, XOR-swizzled LDS, global_load_lds staging.
enum { MODE_QKV = 0, MODE_PROJ = 1, MODE_FC1 = 2, MODE_FC2 = 3 };

template <int MODE, int TM, int TN>
__global__ __launch_bounds__(256, TM == 64 ? 4 : 3) void gemm_bt(
    const _Float16* __restrict__ A, const _Float16* __restrict__ W,
    const float* __restrict__ bias, const float* __restrict__ resid,
    float* __restrict__ outF, _Float16* __restrict__ oq,
    _Float16* __restrict__ okk, _Float16* __restrict__ ov, int K) {
    constexpr int MI = TM / 32;  // row-frags per wave (wave covers TM/2 rows)
    constexpr int NI = TN / 32;  // col-frags per wave (wave covers TN/2 cols)
    constexpr int AI = TM / 32;  // A staging instrs per wave (8 rows each)
    constexpr int BI = TN / 32;  // B staging instrs per wave
    __shared__ _Float16 As[TM * 64];
    __shared__ _Float16 Bs[TN * 64];
    int bm = blockIdx.x * TM, bn = blockIdx.y * TN;
    int tid = threadIdx.x;
    int wave = tid >> 6, lane = tid & 63, quad = lane >> 4, l15 = lane & 15;
    int wrow = (wave >> 1) * (TM / 2), wcol = (wave & 1) * (TN / 2);
    int lr = lane >> 3;                 // row-within-8 for staging
    int sw = ((lane & 7) ^ lr) * 8;     // swizzled source col (halves)
    int rsw = (l15 & 7) * 8;            // read-side swizzle XOR operand (halves)
    f4 acc[MI][NI];
#pragma unroll
    for (int mi = 0; mi < MI; mi++)
#pragma unroll
        for (int ni = 0; ni < NI; ni++) acc[mi][ni] = (f4){0.f, 0.f, 0.f, 0.f};

    const _Float16* ApG[AI];
    _Float16* AsL[AI];
#pragma unroll
    for (int i = 0; i < AI; i++) {
        int r = wave * (TM / 4) + i * 8;
        ApG[i] = A + (size_t)(bm + r + lr) * K + sw;
        AsL[i] = As + r * 64;
    }
    const _Float16* WpG[BI];
    _Float16* BsL[BI];
#pragma unroll
    for (int i = 0; i < BI; i++) {
        int r = wave * (TN / 4) + i * 8;
        WpG[i] = W + (size_t)(bn + r + lr) * K + sw;
        BsL[i] = Bs + r * 64;
    }

    for (int k0 = 0; k0 < K; k0 += 64) {
        __syncthreads();  // previous iter's LDS reads done
#pragma unroll
        for (int i = 0; i < AI; i++) { gl_lds16(ApG[i], AsL[i]); ApG[i] += 64; }
#pragma unroll
        for (int i = 0; i < BI; i++) { gl_lds16(WpG[i], BsL[i]); WpG[i] += 64; }
        __syncthreads();  // vmcnt(0) drain before reads
#pragma unroll
        for (int ks = 0; ks < 2; ks++) {
            h8 af[MI], bfr[NI];
#pragma unroll
            for (int mi = 0; mi < MI; mi++)
                af[mi] = *(const h8*)&As[(wrow + 16 * mi + l15) * 64 +
                                         (((4 * ks + quad) * 8) ^ rsw)];
#pragma unroll
            for (int ni = 0; ni < NI; ni++)
                bfr[ni] = *(const h8*)&Bs[(wcol + 16 * ni + l15) * 64 +
                                          (((4 * ks + quad) * 8) ^ rsw)];
#pragma unroll
            for (int mi = 0; mi < MI; mi++)
#pragma unroll
                for (int ni = 0; ni < NI; ni++)
                    acc[mi][ni] = MFMA16(af[mi], bfr[ni], acc[mi][ni]);
        }
    }

    // epilogue: C/D layout col=lane&15, row=quad*4+j
#pragma unroll
    for (int mi = 0; mi < MI; mi++) {
#pragma unroll
        for (int ni = 0; ni < NI; ni++) {
            int col = bn + wcol + 16 * ni + l15;
            float bc = bias[col];
            int m0 = bm + wrow + 16 * mi + quad * 4;
            float v0 = acc[mi][ni][0] + bc, v1 = acc[mi][ni][1] + bc;
            float v2 = acc[mi][ni][2] + bc, v3 = acc[mi][ni][3] + bc;
            if (MODE == MODE_QKV) {
                int sec = col / 768;           // 0=q 1=k 2=v (uniform per block)
                int rem = col - sec * 768;
                int h = rem >> 6, d = rem & 63;
                int b_ = m0 >> 11, ns = m0 & 2047;
                size_t bh = (size_t)(b_ * 12 + h);
                if (sec == 0) {
                    // Q pre-scaled by 1/8 * log2(e) so attention can use exp2
                    size_t base = (bh * 2048 + ns) * 64 + d;
                    oq[base] = f2h(v0 * 0.18033688f);
                    oq[base + 64] = f2h(v1 * 0.18033688f);
                    oq[base + 128] = f2h(v2 * 0.18033688f);
                    oq[base + 192] = f2h(v3 * 0.18033688f);
                } else if (sec == 1) {
                    size_t base = (bh * 2048 + ns) * 64 + d;
                    okk[base] = f2h(v0);
                    okk[base + 64] = f2h(v1);
                    okk[base + 128] = f2h(v2);
                    okk[base + 192] = f2h(v3);
                } else {
                    *(h4*)&ov[(bh * 64 + d) * 2048 + ns] = pk4(v0, v1, v2, v3);  // V^T
                }
            } else if (MODE == MODE_FC1) {
                // tanh-form GELU: x*sigmoid(1.595769x + 0.142954x^3) via exp
                float g0 = __expf(v0 * (1.5957691f + 0.14295405f * v0 * v0));
                float g1 = __expf(v1 * (1.5957691f + 0.14295405f * v1 * v1));
                float g2 = __expf(v2 * (1.5957691f + 0.14295405f * v2 * v2));
                float g3 = __expf(v3 * (1.5957691f + 0.14295405f * v3 * v3));
                size_t base = (size_t)m0 * 3072 + col;
                oq[base] = f2h(v0 * g0 / (1.f + g0));
                oq[base + 3072] = f2h(v1 * g1 / (1.f + g1));
                oq[base + 6144] = f2h(v2 * g2 / (1.f + g2));
                oq[base + 9216] = f2h(v3 * g3 / (1.f + g3));
            } else {  // PROJ / FC2: + residual -> fp32
                size_t idx = (size_t)m0 * 768 + col;
                outF[idx] = v0 + resid[idx];
                outF[idx + 768] = v1 + resid[idx + 768];
                outF[idx + 1536] = v2 + resid[idx + 1536];
                outF[idx + 2304] = v3 + resid[idx + 2304];
            }
        }
    }
}

// ---------------- Flash attention (R9 config): P direct-register PV, dbuf K/V ----------------
// Q,K [bh,2048,64] (Q pre-scaled by 0.125*log2e), Vt [bh,64,2048] -> O f16 [B,N,768].
// Block (bh, qt): 256 thr / 4 waves x 32 queries, 32 k-tiles, 1 barrier each.
// S^T = K.Q^T (16x16x32); exp2 in regs; PV via 16x16x16 (P = B-operand direct).
__global__ __launch_bounds__(256, 3) void attn_kernel(
    const _Float16* __restrict__ Q, const _Float16* __restrict__ Kp,
    const _Float16* __restrict__ Vt, _Float16* __restrict__ O) {
    int bh = blockIdx.x;   // 48
    int qt = blockIdx.y;   // 16 q-tiles of 128
    int tid = threadIdx.x;
    int wave = tid >> 6, lane = tid & 63, quad = lane >> 4, l15 = lane & 15;
    int lr = lane >> 3;
    int sw = ((lane & 7) ^ lr) * 8;  // staging swizzle (halves)
    int rsw = (l15 & 7) * 8;         // read swizzle (halves)

    __shared__ _Float16 Ks[2 * 64 * 64];  // [key][d]  16 KB dbuf, swizzled
    __shared__ _Float16 Vs[2 * 64 * 64];  // [d][key]  16 KB dbuf, swizzled

    // Q fragments: loop-invariant, straight from global into registers.
    h8 qf[2][2];
    {
        const _Float16* Qb =
            Q + (((size_t)bh * 2048) + qt * 128 + wave * 32 + l15) * 64 + quad * 8;
#pragma unroll
        for (int qc = 0; qc < 2; qc++)
#pragma unroll
            for (int ks = 0; ks < 2; ks++)
                qf[qc][ks] = *(const h8*)(Qb + qc * 16 * 64 + ks * 32);
    }
    h4 ones4;
#pragma unroll
    for (int j = 0; j < 4; j++) ones4[j] = (_Float16)1.0f;

    f4 Oa[4][2];  // [dc][qc]
    f4 Ls[2];     // ones-MFMA row-sum accumulator
#pragma unroll
    for (int dc = 0; dc < 4; dc++)
#pragma unroll
        for (int qc = 0; qc < 2; qc++) Oa[dc][qc] = (f4){0.f, 0.f, 0.f, 0.f};
    Ls[0] = (f4){0.f, 0.f, 0.f, 0.f};
    Ls[1] = (f4){0.f, 0.f, 0.f, 0.f};

    const _Float16* Kg = Kp + (size_t)bh * 2048 * 64;
    const _Float16* Vg = Vt + (size_t)bh * 64 * 2048;
    const _Float16* KpG[2];
    const _Float16* VpG[2];
    int rKV[2];
#pragma unroll
    for (int i = 0; i < 2; i++) {
        rKV[i] = wave * 16 + i * 8;
        KpG[i] = Kg + (size_t)(rKV[i] + lr) * 64 + sw;
        VpG[i] = Vg + (size_t)(rKV[i] + lr) * 2048 + sw;
    }

    // prologue: prefetch tile 0 into buffer 0
#pragma unroll
    for (int i = 0; i < 2; i++) {
        gl_lds16(KpG[i], Ks + rKV[i] * 64); KpG[i] += 4096;
        gl_lds16(VpG[i], Vs + rKV[i] * 64); VpG[i] += 64;
    }

    for (int it = 0; it < 32; it++) {
        int bufC = (it & 1) * 4096, bufN = ((it & 1) ^ 1) * 4096;
        __syncthreads();  // this tile's prefetch done; prev-iter reads done
        if (it + 1 < 32) {
#pragma unroll
            for (int i = 0; i < 2; i++) {
                gl_lds16(KpG[i], Ks + bufN + rKV[i] * 64); KpG[i] += 4096;
                gl_lds16(VpG[i], Vs + bufN + rKV[i] * 64); VpG[i] += 64;
            }
        }

        // S^T = K . Q^T  (C-layout: key=quad*4+j within 16-key block kc, query=l15)
        f4 Sa[4][2];
#pragma unroll
        for (int kc = 0; kc < 4; kc++)
#pragma unroll
            for (int qc = 0; qc < 2; qc++) Sa[kc][qc] = (f4){0.f, 0.f, 0.f, 0.f};
#pragma unroll
        for (int ks = 0; ks < 2; ks++) {
            h8 kf[4];
#pragma unroll
            for (int kc = 0; kc < 4; kc++)
                kf[kc] = *(const h8*)&Ks[bufC + (16 * kc + l15) * 64 +
                                         (((4 * ks + quad) * 8) ^ rsw)];
#pragma unroll
            for (int kc = 0; kc < 4; kc++)
#pragma unroll
                for (int qc = 0; qc < 2; qc++)
                    Sa[kc][qc] = MFMA16(kf[kc], qf[qc][ks], Sa[kc][qc]);
        }

        // p = 2^s in registers — layout already matches 16x16x16 B-operand
        h4 p[4][2];
#pragma unroll
        for (int kc = 0; kc < 4; kc++)
#pragma unroll
            for (int qc = 0; qc < 2; qc++)
                p[kc][qc] = pk4(exp2f(Sa[kc][qc][0]), exp2f(Sa[kc][qc][1]),
                                exp2f(Sa[kc][qc][2]), exp2f(Sa[kc][qc][3]));

        // O^T += V^T . P^T via 16x16x16 (A = V^T h4 frags from LDS, B = p regs)
#pragma unroll
        for (int kc = 0; kc < 4; kc++) {
            h4 vf4[4];
#pragma unroll
            for (int dc = 0; dc < 4; dc++)
                vf4[dc] = *(const h4*)&Vs[bufC + (16 * dc + l15) * 64 +
                                          (((2 * kc + (quad >> 1)) * 8) ^ rsw) +
                                          (quad & 1) * 4];
#pragma unroll
            for (int dc = 0; dc < 4; dc++)
#pragma unroll
                for (int qc = 0; qc < 2; qc++)
                    Oa[dc][qc] = MFMAK16(vf4[dc], p[kc][qc], Oa[dc][qc]);
#pragma unroll
            for (int qc = 0; qc < 2; qc++)
                Ls[qc] = MFMAK16(ones4, p[kc][qc], Ls[qc]);
        }
    }

    // epilogue: O[b, n, h*64 + d] f16, d = 16*dc + quad*4 + j
    int b_ = bh / 12, h = bh - b_ * 12;
#pragma unroll
    for (int qc = 0; qc < 2; qc++) {
        float inv = 1.0f / Ls[qc][0];
        int n = qt * 128 + wave * 32 + 16 * qc + l15;
        size_t base = ((size_t)b_ * 2048 + n) * 768 + h * 64;
#pragma unroll
        for (int dc = 0; dc < 4; dc++) {
            f4 o = Oa[dc][qc];
            *(h4*)&O[base + 16 * dc + quad * 4] =
                pk4(o[0] * inv, o[1] * inv, o[2] * inv, o[3] * inv);
        }
    }
}

// ---------------------------------------------------------------------------
extern "C" void kernel_launch(void* const* d_in, const int* in_sizes, int n_in,
                              void* d_out, int out_size, void* d_ws, size_t ws_size,
                              hipStream_t stream) {
    const float* x      = (const float*)d_in[0];
    const float* ln1_w  = (const float*)d_in[1];
    const float* ln1_b  = (const float*)d_in[2];
    const float* qkv_w  = (const float*)d_in[3];
    const float* qkv_b  = (const float*)d_in[4];
    const float* proj_w = (const float*)d_in[5];
    const float* proj_b = (const float*)d_in[6];
    const float* ln2_w  = (const float*)d_in[7];
    const float* ln2_b  = (const float*)d_in[8];
    const float* fc1_w  = (const float*)d_in[9];
    const float* fc1_b  = (const float*)d_in[10];
    const float* fc2_w  = (const float*)d_in[11];
    const float* fc2_b  = (const float*)d_in[12];
    float* out = (float*)d_out;

    // workspace arena (~77 MB)
    char* ws = (char*)d_ws;
    size_t off = 0;
    _Float16* wqkv  = (_Float16*)(ws + off); off += (size_t)2304 * 768 * 2;
    _Float16* wproj = (_Float16*)(ws + off); off += (size_t)768 * 768 * 2;
    _Float16* wfc1  = (_Float16*)(ws + off); off += (size_t)3072 * 768 * 2;
    _Float16* wfc2  = (_Float16*)(ws + off); off += (size_t)768 * 3072 * 2;
    _Float16* actA  = (_Float16*)(ws + off); off += (size_t)8192 * 768 * 2;   // ln1/attn/ln2 out
    _Float16* big   = (_Float16*)(ws + off); off += (size_t)8192 * 3072 * 2;  // q,k,vT | fc1 out
    _Float16* qb = big;
    _Float16* kb = big + (size_t)48 * 2048 * 64;
    _Float16* vb = big + (size_t)2 * 48 * 2048 * 64;
    _Float16* hb = big;  // reused after attention for gelu(fc1) [8192,3072]

    // one launch for all four weight casts
    cvt_all<<<6912, 256, 0, stream>>>(qkv_w, wqkv, 2304 * 768, proj_w, wproj, 768 * 768,
                                      fc1_w, wfc1, 3072 * 768, fc2_w, wfc2);

    ln_f16<<<8192, 192, 0, stream>>>(x, ln1_w, ln1_b, actA);
    gemm_bt<MODE_QKV, 128, 192><<<dim3(64, 12), 256, 0, stream>>>(actA, wqkv, qkv_b, nullptr,
                                                                  nullptr, qb, kb, vb, 768);
    attn_kernel<<<dim3(48, 16), 256, 0, stream>>>(qb, kb, vb, actA);
    gemm_bt<MODE_PROJ, 64, 128><<<dim3(128, 6), 256, 0, stream>>>(actA, wproj, proj_b, x, out,
                                                                  nullptr, nullptr, nullptr, 768);
    ln_f16<<<8192, 192, 0, stream>>>(out, ln2_w, ln2_b, actA);
    gemm_bt<MODE_FC1, 128, 128><<<dim3(64, 24), 256, 0, stream>>>(actA, wfc1, fc1_b, nullptr,
                                                                  nullptr, hb, nullptr, nullptr, 768);
    gemm_bt<MODE_FC2, 64, 128><<<dim3(128, 6), 256, 0, stream>>>(hb, wfc2, fc2_b, out, out,
                                                                 nullptr, nullptr, nullptr, 3072);
}